// Round 1
// baseline (222.922 us; speedup 1.0000x reference)
//
#include <hip/hip_runtime.h>

// Encoding layer. B=16, C=512, N=4096, K=32.
// v2: attack the latency/serialization bound (all counters low at 512 blocks =
// 2 blocks/CU one-shot). Changes:
//  - 1024 blocks (64-token chunks) -> 4 sequential blocks/CU (2 resident):
//    cross-block overlap of the phase chain.
//  - Full 512c x 64n x-tile staged ONCE to LDS as bf16 (72 KB, persistent);
//    GEMM2 reads it via ds_read_b128 -> no global re-read of x, no f2bf repack.
//  - cw pre-converted to bf16 (+ csq) by a tiny setup kernel into d_ws; GEMM1
//    A-fragments are per-lane 16 B global loads from the 32 KB L1/L2-hot image
//    (prefetched one c-group ahead) -> no 33 KB cwT in LDS.
//  - Epilogue subtracts f32 cw directly (more accurate than bf16 round-trip).
// Partials (1024 x 64 KB = 64 MiB) -> d_ws + reduce kernel.

#define B_ 16
#define C_ 512
#define N_ 4096
#define K_ 32
#define CHUNK 64                 // tokens per block
#define NCH (N_ / CHUNK)         // 64 chunks per batch
#define NBLK (B_ * NCH)          // 1024 blocks
#define XCP 72                   // XC row stride (u16): 144 B, 16B-multiple for b128
#define WLS 40                   // Wl row stride (u16): 80 B, 16B-multiple

typedef __attribute__((ext_vector_type(8))) short short8;
typedef __attribute__((ext_vector_type(16))) float floatx16;

__device__ inline unsigned short f2bf(float f) {
    union { float f; unsigned u; } v; v.f = f;
    unsigned r = v.u + 0x7FFFu + ((v.u >> 16) & 1u);  // RNE
    return (unsigned short)(r >> 16);
}

// cw (f32 [K][C]) -> cwb (bf16 [K][C]) + csq[k] = ||c_k||^2. One 256-thread block.
__global__ __launch_bounds__(256)
void cw_convert(const float* __restrict__ cw, unsigned short* __restrict__ cwb,
                float* __restrict__ csq)
{
    const int tid = threadIdx.x;
    const int k = tid >> 3, q = tid & 7;              // k row, 64-c slice
    const float4* src = (const float4*)(cw + k * C_ + q * 64);
    float s = 0.f;
    #pragma unroll
    for (int i = 0; i < 16; ++i) {
        const float4 v = src[i];
        s += v.x*v.x + v.y*v.y + v.z*v.z + v.w*v.w;
        const unsigned lo = (unsigned)f2bf(v.x) | ((unsigned)f2bf(v.y) << 16);
        const unsigned hi = (unsigned)f2bf(v.z) | ((unsigned)f2bf(v.w) << 16);
        *(uint2*)&cwb[k * C_ + q * 64 + i * 4] = make_uint2(lo, hi);
    }
    s += __shfl_xor(s, 1); s += __shfl_xor(s, 2); s += __shfl_xor(s, 4);
    if (q == 0) csq[k] = s;
}

template <int USE_WS>
__global__ __launch_bounds__(256, 2)
void enc_kernel(const float* __restrict__ x,
                const unsigned short* __restrict__ cwb,
                const float* __restrict__ csqg,
                const float* __restrict__ cw,
                const float* __restrict__ scale,
                float* __restrict__ outp)
{
    __shared__ unsigned short XC[C_ * XCP];      // x bf16 [c][n], 73728 B, persistent
    __shared__ unsigned short Wl[2][K_ * WLS];   // softmax w bf16 [tile][k][n], 5120 B
    __shared__ float xsqp[4][CHUNK];             // ||x_n||^2 wave-partials, 1024 B
    __shared__ float csq[K_];
    __shared__ float scl[K_];

    const int tid  = threadIdx.x;
    const int wave = tid >> 6;
    const int lane = tid & 63;
    const int l31  = lane & 31;
    const int lh   = lane >> 5;

    const int b     = blockIdx.x >> 6;
    const int chunk = blockIdx.x & (NCH - 1);
    const float* xb = x + (long)b * C_ * N_;

    // staging mapping: thread = (r = tid>>4, p = tid&15); per 64-c group it
    // loads 4 rows (c = g*64 + i*16 + r), each as one float4 (tokens p*4..p*4+3).
    const int r = tid >> 4;
    const int p = tid & 15;
    const float* xrow = xb + chunk * CHUNK + p * 4;

    if (tid < K_) { scl[tid] = scale[tid]; csq[tid] = csqg[tid]; }

    float4 s0[4], s1[4], s2[4];          // 3-deep staging ring
#define XISSUE(buf_, g_)                                                       \
    { _Pragma("unroll")                                                        \
      for (int i = 0; i < 4; ++i)                                              \
          buf_[i] = *(const float4*)(xrow + (long)((g_) * 64 + i * 16 + r) * N_); }

    float xs0 = 0.f, xs1 = 0.f, xs2 = 0.f, xs3 = 0.f;
#define XWRITE(buf_, g_)                                                       \
    { _Pragma("unroll")                                                        \
      for (int i = 0; i < 4; ++i) {                                            \
          const float4 v = buf_[i];                                            \
          xs0 += v.x * v.x; xs1 += v.y * v.y;                                  \
          xs2 += v.z * v.z; xs3 += v.w * v.w;                                  \
          const unsigned lo = (unsigned)f2bf(v.x) | ((unsigned)f2bf(v.y) << 16);\
          const unsigned hi = (unsigned)f2bf(v.z) | ((unsigned)f2bf(v.w) << 16);\
          *(uint2*)&XC[((g_) * 64 + i * 16 + r) * XCP + p * 4] = make_uint2(lo, hi);\
      } }

    // GEMM1 A-fragments straight from global bf16 cw image (L1/L2-hot, 32 KB)
    const unsigned short* cwr = cwb + l31 * C_ + lh * 8;
    short8 afA[4], afB[4];
#define AFLOAD(buf_, g_)                                                       \
    { _Pragma("unroll")                                                        \
      for (int s = 0; s < 4; ++s)                                              \
          buf_[s] = *(const short8*)(cwr + (g_) * 64 + s * 16); }

    XISSUE(s0, 0)
    XISSUE(s1, 1)
    if (wave < 2) AFLOAD(afA, 0)
    XWRITE(s0, 0)
    XISSUE(s2, 2)
    __syncthreads();       // XC group 0 ready

    // ================= GEMM1: S[k][n] = cw @ X, c-group pipelined =============
    // waves 0,1 compute (token tile = wave); waves 2,3 only stage.
    floatx16 S;
    #pragma unroll
    for (int i = 0; i < 16; ++i) S[i] = 0.f;

    #pragma unroll
    for (int g = 0; g < 8; ++g) {
        if (g + 3 < 8) {    // issue loads 3 groups ahead (that ring slot is free)
            if      ((g % 3) == 0) XISSUE(s0, g + 3)
            else if ((g % 3) == 1) XISSUE(s1, g + 3)
            else                   XISSUE(s2, g + 3)
        }
        if (wave < 2) {
            if (g + 1 < 8) {
                if (g & 1) AFLOAD(afA, g + 1) else AFLOAD(afB, g + 1)
            }
            #pragma unroll
            for (int s = 0; s < 4; ++s) {
                short8 bx;
                #pragma unroll
                for (int j = 0; j < 8; ++j)
                    bx[j] = (short)XC[(g * 64 + s * 16 + lh * 8 + j) * XCP + wave * 32 + l31];
                S = __builtin_amdgcn_mfma_f32_32x32x16_bf16((g & 1) ? afB[s] : afA[s],
                                                            bx, S, 0, 0, 0);
            }
        }
        if (g + 1 < 8) {
            if      (((g + 1) % 3) == 0) XWRITE(s0, g + 1)
            else if (((g + 1) % 3) == 1) XWRITE(s1, g + 1)
            else                         XWRITE(s2, g + 1)
        }
        if (g < 7) __syncthreads();
    }

    // ---- xsq: threads sharing p are lanes {l, l^16, l^32, l^48} of one wave ----
    xs0 += __shfl_xor(xs0, 16); xs1 += __shfl_xor(xs1, 16);
    xs2 += __shfl_xor(xs2, 16); xs3 += __shfl_xor(xs3, 16);
    xs0 += __shfl_xor(xs0, 32); xs1 += __shfl_xor(xs1, 32);
    xs2 += __shfl_xor(xs2, 32); xs3 += __shfl_xor(xs3, 32);
    if (lane < 16) {
        xsqp[wave][lane * 4 + 0] = xs0; xsqp[wave][lane * 4 + 1] = xs1;
        xsqp[wave][lane * 4 + 2] = xs2; xsqp[wave][lane * 4 + 3] = xs3;
    }
    __syncthreads();   // xsqp + all XC groups ready

    // ---- softmax over k (waves 0,1): lane pair (l, l+32) holds 16 k's each ----
    if (wave < 2) {
        const int n = wave * 32 + l31;
        const float xq = xsqp[0][n] + xsqp[1][n] + xsqp[2][n] + xsqp[3][n];
        float L[16], mx = -3.4e38f;
        #pragma unroll
        for (int rr = 0; rr < 16; ++rr) {
            const int k = (rr & 3) + 8 * (rr >> 2) + 4 * lh;
            L[rr] = scl[k] * (xq - 2.f * S[rr] + csq[k]);
            mx = fmaxf(mx, L[rr]);
        }
        mx = fmaxf(mx, __shfl_xor(mx, 32));
        float sum = 0.f;
        #pragma unroll
        for (int rr = 0; rr < 16; ++rr) { L[rr] = __expf(L[rr] - mx); sum += L[rr]; }
        sum += __shfl_xor(sum, 32);
        const float inv = 1.f / sum;
        #pragma unroll
        for (int rr = 0; rr < 16; ++rr) {
            const int k = (rr & 3) + 8 * (rr >> 2) + 4 * lh;
            Wl[wave][k * WLS + l31] = f2bf(L[rr] * inv);
        }
    }
    __syncthreads();   // Wl handoff

    // ================= GEMM2: enc[k][c] = sum_n W[k][n] x[n][c], all from LDS ====
    short8 aw[4];
    #pragma unroll
    for (int s = 0; s < 4; ++s)
        aw[s] = *(const short8*)&Wl[s >> 1][l31 * WLS + (s & 1) * 16 + lh * 8];

    floatx16 wacc;
    #pragma unroll
    for (int i = 0; i < 16; ++i) wacc[i] = 0.f;
    {
        short8 ones;
        #pragma unroll
        for (int j = 0; j < 8; ++j) ones[j] = (short)0x3F80;
        #pragma unroll
        for (int s = 0; s < 4; ++s)
            wacc = __builtin_amdgcn_mfma_f32_32x32x16_bf16(aw[s], ones, wacc, 0, 0, 0);
    }

    floatx16 acc[4];
    #pragma unroll
    for (int t = 0; t < 4; ++t)
        #pragma unroll
        for (int i = 0; i < 16; ++i) acc[t][i] = 0.f;

    #pragma unroll
    for (int t = 0; t < 4; ++t) {
        const int c = wave * 128 + t * 32 + l31;
        #pragma unroll
        for (int s = 0; s < 4; ++s) {
            const short8 bx = *(const short8*)&XC[c * XCP + s * 16 + lh * 8];
            acc[t] = __builtin_amdgcn_mfma_f32_32x32x16_bf16(aw[s], bx, acc[t], 0, 0, 0);
        }
    }

    // ---- epilogue: val = acc - wsum[k]*cw[k][c] (f32 cw) ----
    float* dst = USE_WS ? (outp + (size_t)blockIdx.x * K_ * C_)
                        : (outp + (size_t)b * K_ * C_);
    #pragma unroll
    for (int t = 0; t < 4; ++t) {
        const int c = wave * 128 + t * 32 + l31;
        #pragma unroll
        for (int rr = 0; rr < 16; ++rr) {
            const int k = (rr & 3) + 8 * (rr >> 2) + 4 * lh;
            const float val = acc[t][rr] - wacc[rr] * cw[k * C_ + c];
            if (USE_WS) dst[k * C_ + c] = val;
            else        atomicAdd(dst + k * C_ + c, val);
        }
    }
}

// out[b][k][c] = sum_{ch<64} part[b*64+ch][k][c];  grid 256 x 256, float4
__global__ __launch_bounds__(256)
void reduce_kernel(const float4* __restrict__ part, float4* __restrict__ out)
{
    const int gid = blockIdx.x * 256 + threadIdx.x;   // 0..65535
    const int bb  = gid >> 12;                        // 4096 float4 per batch
    const int i4  = gid & 4095;
    const float4* p = part + ((size_t)bb * NCH) * 4096 + i4;
    float4 s = make_float4(0.f, 0.f, 0.f, 0.f);
    #pragma unroll 8
    for (int ch = 0; ch < NCH; ++ch) {
        const float4 v = p[(size_t)ch * 4096];
        s.x += v.x; s.y += v.y; s.z += v.z; s.w += v.w;
    }
    out[gid] = s;
}

extern "C" void kernel_launch(void* const* d_in, const int* in_sizes, int n_in,
                              void* d_out, int out_size, void* d_ws, size_t ws_size,
                              hipStream_t stream) {
    const float* x     = (const float*)d_in[0];
    const float* cw    = (const float*)d_in[1];
    const float* scale = (const float*)d_in[2];
    float* out = (float*)d_out;

    // ws layout: [0, 32 KiB) cw bf16 image; [32 KiB, +128 B) csq; partials at 64 KiB
    unsigned short* cwb = (unsigned short*)d_ws;
    float* csq = (float*)((char*)d_ws + (size_t)K_ * C_ * sizeof(unsigned short));
    const size_t part_off = 65536;
    const size_t ws_need = part_off + (size_t)NBLK * K_ * C_ * sizeof(float); // 64 KiB + 64 MiB

    if (ws_size >= ws_need) {
        float* part = (float*)((char*)d_ws + part_off);
        hipLaunchKernelGGL(cw_convert, dim3(1), dim3(256), 0, stream, cw, cwb, csq);
        hipLaunchKernelGGL(enc_kernel<1>, dim3(NBLK), dim3(256), 0, stream,
                           x, cwb, csq, cw, scale, part);
        hipLaunchKernelGGL(reduce_kernel, dim3(256), dim3(256), 0, stream,
                           (const float4*)part, (float4*)out);
    } else {
        hipMemsetAsync(out, 0, (size_t)out_size * sizeof(float), stream);
        hipLaunchKernelGGL(cw_convert, dim3(1), dim3(256), 0, stream, cw, cwb, csq);
        hipLaunchKernelGGL(enc_kernel<0>, dim3(NBLK), dim3(256), 0, stream,
                           x, cwb, csq, cw, scale, out);
    }
}